// Round 1
// baseline (9326.733 us; speedup 1.0000x reference)
//
#include <hip/hip_runtime.h>
#include <hip/hip_bf16.h>
#include <cmath>

// ---------------------------------------------------------------------------
// GEMM: C[N,M] = A[N,K] @ B[K,M], B optionally split as [B0 | B1] halves.
// Weights + A-rows staged in LDS. Block=256, ROWS rows per block.
// ---------------------------------------------------------------------------
template<int K, int M, int ROWS>
__global__ __launch_bounds__(256)
void gemm_kernel(const float* __restrict__ A, const float* __restrict__ B0,
                 const float* __restrict__ B1, float* __restrict__ C, int N)
{
    __shared__ float Bs[K * M];
    __shared__ float As[ROWS * K];
    for (int i = threadIdx.x; i < K * M; i += 256) {
        float v;
        if (B1 != nullptr) {
            int k = i / M, m = i - k * M;
            v = (m < M / 2) ? B0[k * (M / 2) + m] : B1[k * (M / 2) + (m - M / 2)];
        } else {
            v = B0[i];
        }
        Bs[i] = v;
    }
    int row0 = blockIdx.x * ROWS;
    for (int i = threadIdx.x; i < ROWS * K; i += 256) {
        int r = row0 + i / K;
        As[i] = (r < N) ? A[(size_t)r * K + (i % K)] : 0.f;
    }
    __syncthreads();
    for (int o = threadIdx.x; o < ROWS * M; o += 256) {
        int r = o / M, m = o - r * M;
        if (row0 + r >= N) continue;
        float acc = 0.f;
        #pragma unroll 16
        for (int k = 0; k < K; ++k) acc += As[r * K + k] * Bs[k * M + m];
        C[(size_t)(row0 + r) * M + m] = acc;
    }
}

// ---------------------------------------------------------------------------
// Edge kernel: 8 lanes per edge (one per head). Computes
//   ex = exp(sum_c att[h][c] * leaky_relu(xl[src][h][c] + xr[dst][h][c]))
//   num[dst][h][c] += ex * xl[src][h][c];  den[dst][h] += ex
// (no max-subtraction needed: logits are O(1), ratio is exact)
// ---------------------------------------------------------------------------
__global__ __launch_bounds__(256)
void edge_kernel(const int* __restrict__ srcs, const int* __restrict__ dsts,
                 const float* __restrict__ xlr,  // [N,128]: cols 0..63 = xl, 64..127 = xr
                 const float* __restrict__ att,  // [8,8]
                 float* __restrict__ num, float* __restrict__ den, int E)
{
    __shared__ float att_s[64];
    if (threadIdx.x < 64) att_s[threadIdx.x] = att[threadIdx.x];
    __syncthreads();
    long gid = (long)blockIdx.x * 256 + threadIdx.x;
    int e = (int)(gid >> 3);
    if (e >= E) return;
    int h = (int)(gid & 7);
    int src = srcs[e], dst = dsts[e];
    const float4* xl4 = (const float4*)(xlr + (size_t)src * 128 + h * 8);
    const float4* xr4 = (const float4*)(xlr + (size_t)dst * 128 + 64 + h * 8);
    float4 a0 = xl4[0], a1 = xl4[1];
    float4 b0 = xr4[0], b1 = xr4[1];
    float xls[8] = {a0.x, a0.y, a0.z, a0.w, a1.x, a1.y, a1.z, a1.w};
    float xrs[8] = {b0.x, b0.y, b0.z, b0.w, b1.x, b1.y, b1.z, b1.w};
    float logit = 0.f;
    #pragma unroll
    for (int c = 0; c < 8; ++c) {
        float s = xls[c] + xrs[c];
        s = (s > 0.f) ? s : 0.2f * s;
        logit += s * att_s[h * 8 + c];
    }
    float ex = __expf(logit);
    unsafeAtomicAdd(&den[(size_t)dst * 8 + h], ex);
    float* np_ = num + (size_t)dst * 64 + h * 8;
    #pragma unroll
    for (int c = 0; c < 8; ++c) unsafeAtomicAdd(&np_[c], ex * xls[c]);
}

// ---------------------------------------------------------------------------
// finalize + BN-stats: y = num/(den+1e-16) + h_residual  (in place into num),
// plus per-feature sum / sumsq accumulated into stats[0..63], stats[64..127].
// den==nullptr -> pre-layer mode (y = num, no residual).
// ---------------------------------------------------------------------------
__global__ __launch_bounds__(256)
void finalize_stats_kernel(float* __restrict__ y, const float* __restrict__ den,
                           const float* __restrict__ hres, float* __restrict__ stats, int N)
{
    int f  = threadIdx.x & 63;
    int rg = threadIdx.x >> 6;
    float s = 0.f, s2 = 0.f;
    for (int r = blockIdx.x * 4 + rg; r < N; r += gridDim.x * 4) {
        float v = y[(size_t)r * 64 + f];
        if (den != nullptr) {
            v = v / (den[(size_t)r * 8 + (f >> 3)] + 1e-16f) + hres[(size_t)r * 64 + f];
            y[(size_t)r * 64 + f] = v;
        }
        s += v;
        s2 += v * v;
    }
    __shared__ float ls[2][4][64];
    ls[0][rg][f] = s;
    ls[1][rg][f] = s2;
    __syncthreads();
    if (threadIdx.x < 128) {
        int which = threadIdx.x >> 6;
        float a = ls[which][0][f] + ls[which][1][f] + ls[which][2][f] + ls[which][3][f];
        unsafeAtomicAdd(&stats[which * 64 + f], a);
    }
}

// ---------------------------------------------------------------------------
// BN apply + ELU: out = elu(g * (y - mean) * rsqrt(var + 1e-5) + b)
// ---------------------------------------------------------------------------
__global__ __launch_bounds__(256)
void bn_apply_elu_kernel(const float* __restrict__ y, const float* __restrict__ stats,
                         const float* __restrict__ g, const float* __restrict__ b,
                         float* __restrict__ out, int N, float invN)
{
    __shared__ float sg[64], sb[64], sm[64], sv[64];
    if (threadIdx.x < 64) {
        int f = threadIdx.x;
        float m   = stats[f] * invN;
        float var = stats[64 + f] * invN - m * m;
        sm[f] = m;
        sv[f] = rsqrtf(var + 1e-5f);
        sg[f] = g[f];
        sb[f] = b[f];
    }
    __syncthreads();
    size_t total = (size_t)N * 64;
    for (size_t i = (size_t)blockIdx.x * 256 + threadIdx.x; i < total;
         i += (size_t)gridDim.x * 256) {
        int f = (int)(i & 63);
        float t = sg[f] * ((y[i] - sm[f]) * sv[f]) + sb[f];
        out[i] = (t > 0.f) ? t : expm1f(t);
    }
}

// ---------------------------------------------------------------------------
// MLP head: per-node 64->48->32->16->2 with ELU between; weights in LDS
// (uniform-address broadcast reads, conflict-free).
// ---------------------------------------------------------------------------
__global__ __launch_bounds__(256)
void mlp_kernel(const float* __restrict__ h,
                const float* __restrict__ W1, const float* __restrict__ B1,
                const float* __restrict__ W2, const float* __restrict__ B2,
                const float* __restrict__ W3, const float* __restrict__ B3,
                const float* __restrict__ W4, const float* __restrict__ B4,
                float* __restrict__ out, int N)
{
    __shared__ float w1[64 * 48], w2[48 * 32], w3[32 * 16], w4[16 * 2];
    __shared__ float bb1[48], bb2[32], bb3[16], bb4[2];
    for (int i = threadIdx.x; i < 64 * 48; i += 256) w1[i] = W1[i];
    for (int i = threadIdx.x; i < 48 * 32; i += 256) w2[i] = W2[i];
    for (int i = threadIdx.x; i < 32 * 16; i += 256) w3[i] = W3[i];
    for (int i = threadIdx.x; i < 16 * 2;  i += 256) w4[i] = W4[i];
    if (threadIdx.x < 48) bb1[threadIdx.x] = B1[threadIdx.x];
    if (threadIdx.x < 32) bb2[threadIdx.x] = B2[threadIdx.x];
    if (threadIdx.x < 16) bb3[threadIdx.x] = B3[threadIdx.x];
    if (threadIdx.x < 2)  bb4[threadIdx.x] = B4[threadIdx.x];
    __syncthreads();
    int n = blockIdx.x * 256 + threadIdx.x;
    if (n >= N) return;
    float a[64];
    const float4* hp = (const float4*)(h + (size_t)n * 64);
    #pragma unroll
    for (int i = 0; i < 16; ++i) {
        float4 v = hp[i];
        a[4 * i] = v.x; a[4 * i + 1] = v.y; a[4 * i + 2] = v.z; a[4 * i + 3] = v.w;
    }
    float t1[48];
    for (int j = 0; j < 48; ++j) {
        float acc = bb1[j];
        #pragma unroll
        for (int k = 0; k < 64; ++k) acc += a[k] * w1[k * 48 + j];
        t1[j] = (acc > 0.f) ? acc : expm1f(acc);
    }
    float t2[32];
    for (int j = 0; j < 32; ++j) {
        float acc = bb2[j];
        #pragma unroll
        for (int k = 0; k < 48; ++k) acc += t1[k] * w2[k * 32 + j];
        t2[j] = (acc > 0.f) ? acc : expm1f(acc);
    }
    float t3[16];
    for (int j = 0; j < 16; ++j) {
        float acc = bb3[j];
        #pragma unroll
        for (int k = 0; k < 32; ++k) acc += t2[k] * w3[k * 16 + j];
        t3[j] = (acc > 0.f) ? acc : expm1f(acc);
    }
    float o0 = bb4[0], o1 = bb4[1];
    #pragma unroll
    for (int k = 0; k < 16; ++k) {
        o0 += t3[k] * w4[k * 2 + 0];
        o1 += t3[k] * w4[k * 2 + 1];
    }
    out[(size_t)n * 2 + 0] = o0;
    out[(size_t)n * 2 + 1] = o1;
}

// ---------------------------------------------------------------------------
extern "C" void kernel_launch(void* const* d_in, const int* in_sizes, int n_in,
                              void* d_out, int out_size, void* d_ws, size_t ws_size,
                              hipStream_t stream)
{
    const float* x    = (const float*)d_in[0];
    const int*   ei   = (const int*)d_in[1];
    const float* Wpre = (const float*)d_in[2];
    const float* g0   = (const float*)d_in[3];
    const float* b0   = (const float*)d_in[4];

    const int N = in_sizes[0] / 128;
    const int E = in_sizes[1] / 2;
    const float invN = 1.f / (float)N;

    float* ws    = (float*)d_ws;
    float* h     = ws;                        // N*64
    float* xlr   = h + (size_t)N * 64;        // N*128
    float* num   = xlr + (size_t)N * 128;     // N*64
    float* den   = num + (size_t)N * 64;      // N*8
    float* stats = den + (size_t)N * 8;       // 128

    const int* srcs = ei;
    const int* dsts = ei + E;

    // ---- pre-layer: h = elu(bn(x @ Wpre)) ----
    gemm_kernel<128, 64, 16><<<(N + 15) / 16, 256, 0, stream>>>(x, Wpre, nullptr, num, N);
    hipMemsetAsync(stats, 0, 128 * sizeof(float), stream);
    finalize_stats_kernel<<<1024, 256, 0, stream>>>(num, nullptr, nullptr, stats, N);
    bn_apply_elu_kernel<<<2048, 256, 0, stream>>>(num, stats, g0, b0, h, N, invN);

    // ---- 4 GATv2 layers ----
    for (int l = 0; l < 4; ++l) {
        const float* Wl  = (const float*)d_in[5 + 5 * l + 0];
        const float* Wr  = (const float*)d_in[5 + 5 * l + 1];
        const float* att = (const float*)d_in[5 + 5 * l + 2];
        const float* g   = (const float*)d_in[5 + 5 * l + 3];
        const float* b   = (const float*)d_in[5 + 5 * l + 4];

        gemm_kernel<64, 128, 16><<<(N + 15) / 16, 256, 0, stream>>>(h, Wl, Wr, xlr, N);
        hipMemsetAsync(num, 0, (size_t)N * 64 * sizeof(float), stream);
        hipMemsetAsync(den, 0, (size_t)N * 8 * sizeof(float), stream);
        hipMemsetAsync(stats, 0, 128 * sizeof(float), stream);

        long threads = (long)E * 8;
        edge_kernel<<<(int)((threads + 255) / 256), 256, 0, stream>>>(
            srcs, dsts, xlr, att, num, den, E);

        finalize_stats_kernel<<<1024, 256, 0, stream>>>(num, den, h, stats, N);
        bn_apply_elu_kernel<<<2048, 256, 0, stream>>>(num, stats, g, b, h, N, invN);
    }

    // ---- MLP head ----
    const float* Wp1 = (const float*)d_in[25]; const float* bp1 = (const float*)d_in[26];
    const float* Wp2 = (const float*)d_in[27]; const float* bp2 = (const float*)d_in[28];
    const float* Wp3 = (const float*)d_in[29]; const float* bp3 = (const float*)d_in[30];
    const float* Wp4 = (const float*)d_in[31]; const float* bp4 = (const float*)d_in[32];
    mlp_kernel<<<(N + 255) / 256, 256, 0, stream>>>(
        h, Wp1, bp1, Wp2, bp2, Wp3, bp3, Wp4, bp4, (float*)d_out, N);
}

// Round 2
// 1213.761 us; speedup vs baseline: 7.6842x; 7.6842x over previous
//
#include <hip/hip_runtime.h>
#include <hip/hip_bf16.h>
#include <cmath>

// ---------------------------------------------------------------------------
// GEMM: C[N,M] = A[N,K] @ B[K,M], B optionally split as [B0 | B1] halves.
// ---------------------------------------------------------------------------
template<int K, int M, int ROWS>
__global__ __launch_bounds__(256)
void gemm_kernel(const float* __restrict__ A, const float* __restrict__ B0,
                 const float* __restrict__ B1, float* __restrict__ C, int N)
{
    __shared__ float Bs[K * M];
    __shared__ float As[ROWS * K];
    for (int i = threadIdx.x; i < K * M; i += 256) {
        float v;
        if (B1 != nullptr) {
            int k = i / M, m = i - k * M;
            v = (m < M / 2) ? B0[k * (M / 2) + m] : B1[k * (M / 2) + (m - M / 2)];
        } else {
            v = B0[i];
        }
        Bs[i] = v;
    }
    int row0 = blockIdx.x * ROWS;
    for (int i = threadIdx.x; i < ROWS * K; i += 256) {
        int r = row0 + i / K;
        As[i] = (r < N) ? A[(size_t)r * K + (i % K)] : 0.f;
    }
    __syncthreads();
    for (int o = threadIdx.x; o < ROWS * M; o += 256) {
        int r = o / M, m = o - r * M;
        if (row0 + r >= N) continue;
        float acc = 0.f;
        #pragma unroll 16
        for (int k = 0; k < K; ++k) acc += As[r * K + k] * Bs[k * M + m];
        C[(size_t)(row0 + r) * M + m] = acc;
    }
}

// ---------------------------------------------------------------------------
// CSR build: histogram of dst, exclusive scan, scatter src by dst.
// ---------------------------------------------------------------------------
__global__ __launch_bounds__(256)
void hist_kernel(const int* __restrict__ dsts, int* __restrict__ deg, int E)
{
    int e = blockIdx.x * 256 + threadIdx.x;
    if (e < E) atomicAdd(&deg[dsts[e]], 1);
}

__global__ __launch_bounds__(1024)
void scan_kernel(const int* __restrict__ deg, int* __restrict__ row_ptr,
                 int* __restrict__ cursor, int N)
{
    __shared__ int buf[1024];
    __shared__ int carry;
    if (threadIdx.x == 0) carry = 0;
    __syncthreads();
    for (int base = 0; base < N; base += 1024) {
        int i = base + threadIdx.x;
        int v = (i < N) ? deg[i] : 0;
        buf[threadIdx.x] = v;
        __syncthreads();
        for (int off = 1; off < 1024; off <<= 1) {
            int t = (threadIdx.x >= off) ? buf[threadIdx.x - off] : 0;
            __syncthreads();
            buf[threadIdx.x] += t;
            __syncthreads();
        }
        int incl = buf[threadIdx.x];
        int excl = incl - v;
        if (i < N) { row_ptr[i] = carry + excl; cursor[i] = carry + excl; }
        __syncthreads();
        if (threadIdx.x == 1023) carry += incl;
        __syncthreads();
    }
    if (threadIdx.x == 0) row_ptr[N] = carry;
}

__global__ __launch_bounds__(256)
void scatter_kernel(const int* __restrict__ srcs, const int* __restrict__ dsts,
                    int* __restrict__ cursor, int* __restrict__ col, int E)
{
    int e = blockIdx.x * 256 + threadIdx.x;
    if (e < E) {
        int pos = atomicAdd(&cursor[dsts[e]], 1);
        col[pos] = srcs[e];
    }
}

// ---------------------------------------------------------------------------
// Node-centric GATv2 aggregation: one wave per dst node, lane = feature
// (h = lane>>3, c = lane&7). Registers accumulate num/den; no atomics.
//   y[n] = num/(den+1e-16) + hres[n]
// ---------------------------------------------------------------------------
__global__ __launch_bounds__(256)
void gat_node_kernel(const int* __restrict__ row_ptr, const int* __restrict__ col,
                     const float* __restrict__ xlr,  // [N,128]: xl | xr
                     const float* __restrict__ att,  // [64]
                     const float* __restrict__ hres, float* __restrict__ y, int N)
{
    int lane = threadIdx.x & 63;
    int n = blockIdx.x * 4 + (threadIdx.x >> 6);
    if (n >= N) return;
    float attv = att[lane];
    float xr = xlr[(size_t)n * 128 + 64 + lane];
    int beg = row_ptr[n], end = row_ptr[n + 1];
    float acc = 0.f, den = 0.f;
    int srcn = 0; float xln = 0.f;
    if (beg < end) { srcn = col[beg]; xln = xlr[(size_t)srcn * 128 + lane]; }
    for (int j = beg; j < end; ++j) {
        float xl = xln;
        int jn = j + 1;
        if (jn < end) { int s = col[jn]; xln = xlr[(size_t)s * 128 + lane]; }
        float sum = xl + xr;
        float lr = (sum > 0.f) ? sum : 0.2f * sum;
        float t = lr * attv;
        t += __shfl_xor(t, 1);
        t += __shfl_xor(t, 2);
        t += __shfl_xor(t, 4);
        float ex = __expf(t);
        acc = fmaf(ex, xl, acc);
        den += ex;
    }
    y[(size_t)n * 64 + lane] = acc / (den + 1e-16f) + hres[(size_t)n * 64 + lane];
}

// ---------------------------------------------------------------------------
// BN batch-stats: per-feature sum / sumsq into stats[0..63] / stats[64..127].
// ---------------------------------------------------------------------------
__global__ __launch_bounds__(256)
void stats_kernel(const float* __restrict__ y, float* __restrict__ stats, int N)
{
    int f  = threadIdx.x & 63;
    int rg = threadIdx.x >> 6;
    float s = 0.f, s2 = 0.f;
    for (int r = blockIdx.x * 4 + rg; r < N; r += gridDim.x * 4) {
        float v = y[(size_t)r * 64 + f];
        s += v;
        s2 += v * v;
    }
    __shared__ float ls[2][4][64];
    ls[0][rg][f] = s;
    ls[1][rg][f] = s2;
    __syncthreads();
    if (threadIdx.x < 128) {
        int which = threadIdx.x >> 6;
        float a = ls[which][0][f] + ls[which][1][f] + ls[which][2][f] + ls[which][3][f];
        unsafeAtomicAdd(&stats[which * 64 + f], a);
    }
}

// ---------------------------------------------------------------------------
// BN apply + ELU
// ---------------------------------------------------------------------------
__global__ __launch_bounds__(256)
void bn_apply_elu_kernel(const float* __restrict__ y, const float* __restrict__ stats,
                         const float* __restrict__ g, const float* __restrict__ b,
                         float* __restrict__ out, int N, float invN)
{
    __shared__ float sg[64], sb[64], sm[64], sv[64];
    if (threadIdx.x < 64) {
        int f = threadIdx.x;
        float m   = stats[f] * invN;
        float var = stats[64 + f] * invN - m * m;
        sm[f] = m;
        sv[f] = rsqrtf(var + 1e-5f);
        sg[f] = g[f];
        sb[f] = b[f];
    }
    __syncthreads();
    size_t total = (size_t)N * 64;
    for (size_t i = (size_t)blockIdx.x * 256 + threadIdx.x; i < total;
         i += (size_t)gridDim.x * 256) {
        int f = (int)(i & 63);
        float t = sg[f] * ((y[i] - sm[f]) * sv[f]) + sb[f];
        out[i] = (t > 0.f) ? t : expm1f(t);
    }
}

// ---------------------------------------------------------------------------
// MLP head: per-node 64->48->32->16->2, weights in LDS.
// ---------------------------------------------------------------------------
__global__ __launch_bounds__(256)
void mlp_kernel(const float* __restrict__ h,
                const float* __restrict__ W1, const float* __restrict__ B1,
                const float* __restrict__ W2, const float* __restrict__ B2,
                const float* __restrict__ W3, const float* __restrict__ B3,
                const float* __restrict__ W4, const float* __restrict__ B4,
                float* __restrict__ out, int N)
{
    __shared__ float w1[64 * 48], w2[48 * 32], w3[32 * 16], w4[16 * 2];
    __shared__ float bb1[48], bb2[32], bb3[16], bb4[2];
    for (int i = threadIdx.x; i < 64 * 48; i += 256) w1[i] = W1[i];
    for (int i = threadIdx.x; i < 48 * 32; i += 256) w2[i] = W2[i];
    for (int i = threadIdx.x; i < 32 * 16; i += 256) w3[i] = W3[i];
    for (int i = threadIdx.x; i < 16 * 2;  i += 256) w4[i] = W4[i];
    if (threadIdx.x < 48) bb1[threadIdx.x] = B1[threadIdx.x];
    if (threadIdx.x < 32) bb2[threadIdx.x] = B2[threadIdx.x];
    if (threadIdx.x < 16) bb3[threadIdx.x] = B3[threadIdx.x];
    if (threadIdx.x < 2)  bb4[threadIdx.x] = B4[threadIdx.x];
    __syncthreads();
    int n = blockIdx.x * 256 + threadIdx.x;
    if (n >= N) return;
    float a[64];
    const float4* hp = (const float4*)(h + (size_t)n * 64);
    #pragma unroll
    for (int i = 0; i < 16; ++i) {
        float4 v = hp[i];
        a[4 * i] = v.x; a[4 * i + 1] = v.y; a[4 * i + 2] = v.z; a[4 * i + 3] = v.w;
    }
    float t1[48];
    for (int j = 0; j < 48; ++j) {
        float acc = bb1[j];
        #pragma unroll
        for (int k = 0; k < 64; ++k) acc += a[k] * w1[k * 48 + j];
        t1[j] = (acc > 0.f) ? acc : expm1f(acc);
    }
    float t2[32];
    for (int j = 0; j < 32; ++j) {
        float acc = bb2[j];
        #pragma unroll
        for (int k = 0; k < 48; ++k) acc += t1[k] * w2[k * 32 + j];
        t2[j] = (acc > 0.f) ? acc : expm1f(acc);
    }
    float t3[16];
    for (int j = 0; j < 16; ++j) {
        float acc = bb3[j];
        #pragma unroll
        for (int k = 0; k < 32; ++k) acc += t2[k] * w3[k * 16 + j];
        t3[j] = (acc > 0.f) ? acc : expm1f(acc);
    }
    float o0 = bb4[0], o1 = bb4[1];
    #pragma unroll
    for (int k = 0; k < 16; ++k) {
        o0 += t3[k] * w4[k * 2 + 0];
        o1 += t3[k] * w4[k * 2 + 1];
    }
    out[(size_t)n * 2 + 0] = o0;
    out[(size_t)n * 2 + 1] = o1;
}

// ---------------------------------------------------------------------------
extern "C" void kernel_launch(void* const* d_in, const int* in_sizes, int n_in,
                              void* d_out, int out_size, void* d_ws, size_t ws_size,
                              hipStream_t stream)
{
    const float* x    = (const float*)d_in[0];
    const int*   ei   = (const int*)d_in[1];
    const float* Wpre = (const float*)d_in[2];
    const float* g0   = (const float*)d_in[3];
    const float* b0   = (const float*)d_in[4];

    const int N = in_sizes[0] / 128;
    const int E = in_sizes[1] / 2;
    const float invN = 1.f / (float)N;

    float* ws      = (float*)d_ws;
    float* h       = ws;                      // N*64
    float* xlr     = h + (size_t)N * 64;      // N*128
    float* y       = xlr + (size_t)N * 128;   // N*64
    float* stats   = y + (size_t)N * 64;      // 128
    int*   deg     = (int*)(stats + 128);     // N
    int*   row_ptr = deg + N;                 // N+1
    int*   cursor  = row_ptr + N + 1;         // N
    int*   col     = cursor + N;              // E

    const int* srcs = ei;
    const int* dsts = ei + E;

    // ---- CSR build (once) ----
    hipMemsetAsync(deg, 0, (size_t)N * sizeof(int), stream);
    hist_kernel<<<(E + 255) / 256, 256, 0, stream>>>(dsts, deg, E);
    scan_kernel<<<1, 1024, 0, stream>>>(deg, row_ptr, cursor, N);
    scatter_kernel<<<(E + 255) / 256, 256, 0, stream>>>(srcs, dsts, cursor, col, E);

    // ---- pre-layer: h = elu(bn(x @ Wpre)) ----
    gemm_kernel<128, 64, 16><<<(N + 15) / 16, 256, 0, stream>>>(x, Wpre, nullptr, y, N);
    hipMemsetAsync(stats, 0, 128 * sizeof(float), stream);
    stats_kernel<<<1024, 256, 0, stream>>>(y, stats, N);
    bn_apply_elu_kernel<<<2048, 256, 0, stream>>>(y, stats, g0, b0, h, N, invN);

    // ---- 4 GATv2 layers ----
    for (int l = 0; l < 4; ++l) {
        const float* Wl  = (const float*)d_in[5 + 5 * l + 0];
        const float* Wr  = (const float*)d_in[5 + 5 * l + 1];
        const float* att = (const float*)d_in[5 + 5 * l + 2];
        const float* g   = (const float*)d_in[5 + 5 * l + 3];
        const float* b   = (const float*)d_in[5 + 5 * l + 4];

        gemm_kernel<64, 128, 16><<<(N + 15) / 16, 256, 0, stream>>>(h, Wl, Wr, xlr, N);
        gat_node_kernel<<<(N + 3) / 4, 256, 0, stream>>>(row_ptr, col, xlr, att, h, y, N);
        hipMemsetAsync(stats, 0, 128 * sizeof(float), stream);
        stats_kernel<<<1024, 256, 0, stream>>>(y, stats, N);
        bn_apply_elu_kernel<<<2048, 256, 0, stream>>>(y, stats, g, b, h, N, invN);
    }

    // ---- MLP head ----
    const float* Wp1 = (const float*)d_in[25]; const float* bp1 = (const float*)d_in[26];
    const float* Wp2 = (const float*)d_in[27]; const float* bp2 = (const float*)d_in[28];
    const float* Wp3 = (const float*)d_in[29]; const float* bp3 = (const float*)d_in[30];
    const float* Wp4 = (const float*)d_in[31]; const float* bp4 = (const float*)d_in[32];
    mlp_kernel<<<(N + 255) / 256, 256, 0, stream>>>(
        h, Wp1, bp1, Wp2, bp2, Wp3, bp3, Wp4, bp4, (float*)d_out, N);
}

// Round 3
// 871.386 us; speedup vs baseline: 10.7033x; 1.3929x over previous
//
#include <hip/hip_runtime.h>
#include <hip/hip_bf16.h>
#include <cmath>

// ---------------------------------------------------------------------------
// Fused BN(+ELU) + GEMM: C[N,M] = act(A)[N,K] @ [B0|B1], where
// act(v) = stats ? elu(g*(v-mean)*rsqrt(var+eps)+b) : v.
// Also writes act(A) to hout (residual) when stats != nullptr.
// ---------------------------------------------------------------------------
template<int K, int M, int ROWS>
__global__ __launch_bounds__(256)
void bn_gemm_kernel(const float* __restrict__ A, const float* __restrict__ B0,
                    const float* __restrict__ B1, float* __restrict__ C,
                    const float* __restrict__ stats, const float* __restrict__ g,
                    const float* __restrict__ b, float* __restrict__ hout,
                    int N, float invN)
{
    __shared__ float Bs[K * M];
    __shared__ float As[ROWS * K];
    __shared__ float sm[K], sv[K], sg[K], sb[K];
    if (stats != nullptr && threadIdx.x < K) {
        int f = threadIdx.x;
        float m   = stats[f] * invN;
        float var = stats[K + f] * invN - m * m;
        sm[f] = m;
        sv[f] = rsqrtf(var + 1e-5f);
        sg[f] = g[f];
        sb[f] = b[f];
    }
    for (int i = threadIdx.x; i < K * M; i += 256) {
        float v;
        if (B1 != nullptr) {
            int k = i / M, m = i - k * M;
            v = (m < M / 2) ? B0[k * (M / 2) + m] : B1[k * (M / 2) + (m - M / 2)];
        } else {
            v = B0[i];
        }
        Bs[i] = v;
    }
    __syncthreads();
    int row0 = blockIdx.x * ROWS;
    for (int i = threadIdx.x; i < ROWS * K; i += 256) {
        int r = row0 + i / K, k = i % K;
        float v = (r < N) ? A[(size_t)r * K + k] : 0.f;
        if (stats != nullptr) {
            float t = sg[k] * ((v - sm[k]) * sv[k]) + sb[k];
            v = (t > 0.f) ? t : expm1f(t);
            if (r < N) hout[(size_t)r * K + k] = v;
        }
        As[i] = v;
    }
    __syncthreads();
    for (int o = threadIdx.x; o < ROWS * M; o += 256) {
        int r = o / M, m = o - r * M;
        if (row0 + r >= N) continue;
        float acc = 0.f;
        #pragma unroll 16
        for (int k = 0; k < K; ++k) acc += As[r * K + k] * Bs[k * M + m];
        C[(size_t)(row0 + r) * M + m] = acc;
    }
}

// ---------------------------------------------------------------------------
// CSR build: histogram, 3-phase parallel scan, scatter.
// ---------------------------------------------------------------------------
__global__ __launch_bounds__(256)
void hist_kernel(const int* __restrict__ dsts, int* __restrict__ deg, int E)
{
    int e = blockIdx.x * 256 + threadIdx.x;
    if (e < E) atomicAdd(&deg[dsts[e]], 1);
}

__global__ __launch_bounds__(256)
void scan_partials_kernel(const int* __restrict__ deg, int* __restrict__ part, int N)
{
    int base = blockIdx.x * 2048;
    int s = 0;
    for (int i = threadIdx.x; i < 2048; i += 256) {
        int idx = base + i;
        if (idx < N) s += deg[idx];
    }
    #pragma unroll
    for (int off = 32; off > 0; off >>= 1) s += __shfl_xor(s, off);
    __shared__ int ws[4];
    if ((threadIdx.x & 63) == 0) ws[threadIdx.x >> 6] = s;
    __syncthreads();
    if (threadIdx.x == 0) part[blockIdx.x] = ws[0] + ws[1] + ws[2] + ws[3];
}

__global__ __launch_bounds__(256)
void scan_scan_kernel(int* __restrict__ part, int nb)
{
    __shared__ int buf[256];
    int v = (threadIdx.x < nb) ? part[threadIdx.x] : 0;
    buf[threadIdx.x] = v;
    __syncthreads();
    for (int off = 1; off < 256; off <<= 1) {
        int t = (threadIdx.x >= off) ? buf[threadIdx.x - off] : 0;
        __syncthreads();
        buf[threadIdx.x] += t;
        __syncthreads();
    }
    if (threadIdx.x < nb) part[threadIdx.x] = buf[threadIdx.x] - v;  // exclusive
}

__global__ __launch_bounds__(256)
void scan_final_kernel(const int* __restrict__ deg, const int* __restrict__ part,
                       int* __restrict__ row_ptr, int* __restrict__ cursor, int N, int E)
{
    int base = blockIdx.x * 2048;
    int idx0 = base + threadIdx.x * 8;
    int v[8];
    int s = 0;
    #pragma unroll
    for (int d = 0; d < 8; ++d) {
        int idx = idx0 + d;
        v[d] = (idx < N) ? deg[idx] : 0;
        s += v[d];
    }
    __shared__ int buf[256];
    buf[threadIdx.x] = s;
    __syncthreads();
    for (int off = 1; off < 256; off <<= 1) {
        int t = (threadIdx.x >= off) ? buf[threadIdx.x - off] : 0;
        __syncthreads();
        buf[threadIdx.x] += t;
        __syncthreads();
    }
    int excl = buf[threadIdx.x] - s + part[blockIdx.x];
    #pragma unroll
    for (int d = 0; d < 8; ++d) {
        int idx = idx0 + d;
        if (idx < N) { row_ptr[idx] = excl; cursor[idx] = excl; }
        excl += v[d];
    }
    if (blockIdx.x == 0 && threadIdx.x == 0) row_ptr[N] = E;
}

__global__ __launch_bounds__(256)
void scatter_kernel(const int* __restrict__ srcs, const int* __restrict__ dsts,
                    int* __restrict__ cursor, int* __restrict__ col, int E)
{
    int e = blockIdx.x * 256 + threadIdx.x;
    if (e < E) {
        int pos = atomicAdd(&cursor[dsts[e]], 1);
        col[pos] = srcs[e];
    }
}

// ---------------------------------------------------------------------------
// Node-centric GATv2 + residual + BN-stats. Grid-stride, one wave per node,
// lane = feature. Edge gathers software-pipelined in chunks of 8.
// ---------------------------------------------------------------------------
__global__ __launch_bounds__(256)
void gat_node_kernel(const int* __restrict__ row_ptr, const int* __restrict__ col,
                     const float* __restrict__ xlr, const float* __restrict__ att,
                     const float* __restrict__ hres, float* __restrict__ z,
                     float* __restrict__ stats, int N)
{
    int lane = threadIdx.x & 63;
    int wid  = threadIdx.x >> 6;
    float attv = att[lane];
    float s = 0.f, s2 = 0.f;
    for (int n = blockIdx.x * 4 + wid; n < N; n += gridDim.x * 4) {
        float xr = xlr[(size_t)n * 128 + 64 + lane];
        int beg = row_ptr[n], end = row_ptr[n + 1];
        float acc = 0.f, den = 0.f;
        int j = beg;
        for (; j + 8 <= end; j += 8) {
            float xl[8];
            #pragma unroll
            for (int d = 0; d < 8; ++d)
                xl[d] = xlr[(size_t)col[j + d] * 128 + lane];
            #pragma unroll
            for (int d = 0; d < 8; ++d) {
                float sum = xl[d] + xr;
                float lr = (sum > 0.f) ? sum : 0.2f * sum;
                float t = lr * attv;
                t += __shfl_xor(t, 1);
                t += __shfl_xor(t, 2);
                t += __shfl_xor(t, 4);
                float ex = __expf(t);
                acc = fmaf(ex, xl[d], acc);
                den += ex;
            }
        }
        for (; j < end; ++j) {
            float xl = xlr[(size_t)col[j] * 128 + lane];
            float sum = xl + xr;
            float lr = (sum > 0.f) ? sum : 0.2f * sum;
            float t = lr * attv;
            t += __shfl_xor(t, 1);
            t += __shfl_xor(t, 2);
            t += __shfl_xor(t, 4);
            float ex = __expf(t);
            acc = fmaf(ex, xl, acc);
            den += ex;
        }
        float v = acc / (den + 1e-16f) + hres[(size_t)n * 64 + lane];
        z[(size_t)n * 64 + lane] = v;
        s += v;
        s2 += v * v;
    }
    __shared__ float ls[2][4][64];
    ls[0][wid][lane] = s;
    ls[1][wid][lane] = s2;
    __syncthreads();
    if (threadIdx.x < 128) {
        int which = threadIdx.x >> 6;
        int f = threadIdx.x & 63;
        float a = ls[which][0][f] + ls[which][1][f] + ls[which][2][f] + ls[which][3][f];
        unsafeAtomicAdd(&stats[which * 64 + f], a);
    }
}

// ---------------------------------------------------------------------------
// BN-stats over a plain array (pre-layer only).
// ---------------------------------------------------------------------------
__global__ __launch_bounds__(256)
void stats_kernel(const float* __restrict__ y, float* __restrict__ stats, int N)
{
    int f  = threadIdx.x & 63;
    int rg = threadIdx.x >> 6;
    float s = 0.f, s2 = 0.f;
    for (int r = blockIdx.x * 4 + rg; r < N; r += gridDim.x * 4) {
        float v = y[(size_t)r * 64 + f];
        s += v;
        s2 += v * v;
    }
    __shared__ float ls[2][4][64];
    ls[0][rg][f] = s;
    ls[1][rg][f] = s2;
    __syncthreads();
    if (threadIdx.x < 128) {
        int which = threadIdx.x >> 6;
        float a = ls[which][0][f] + ls[which][1][f] + ls[which][2][f] + ls[which][3][f];
        unsafeAtomicAdd(&stats[which * 64 + f], a);
    }
}

// ---------------------------------------------------------------------------
// MLP head with fused BN+ELU on the input: 64->48->32->16->2.
// ---------------------------------------------------------------------------
__global__ __launch_bounds__(256)
void mlp_kernel(const float* __restrict__ z, const float* __restrict__ stats,
                const float* __restrict__ g, const float* __restrict__ b,
                const float* __restrict__ W1, const float* __restrict__ B1,
                const float* __restrict__ W2, const float* __restrict__ B2,
                const float* __restrict__ W3, const float* __restrict__ B3,
                const float* __restrict__ W4, const float* __restrict__ B4,
                float* __restrict__ out, int N, float invN)
{
    __shared__ float w1[64 * 48], w2[48 * 32], w3[32 * 16], w4[16 * 2];
    __shared__ float bb1[48], bb2[32], bb3[16], bb4[2];
    __shared__ float sm[64], sv[64], sg[64], sb[64];
    for (int i = threadIdx.x; i < 64 * 48; i += 256) w1[i] = W1[i];
    for (int i = threadIdx.x; i < 48 * 32; i += 256) w2[i] = W2[i];
    for (int i = threadIdx.x; i < 32 * 16; i += 256) w3[i] = W3[i];
    for (int i = threadIdx.x; i < 16 * 2;  i += 256) w4[i] = W4[i];
    if (threadIdx.x < 48) bb1[threadIdx.x] = B1[threadIdx.x];
    if (threadIdx.x < 32) bb2[threadIdx.x] = B2[threadIdx.x];
    if (threadIdx.x < 16) bb3[threadIdx.x] = B3[threadIdx.x];
    if (threadIdx.x < 2)  bb4[threadIdx.x] = B4[threadIdx.x];
    if (threadIdx.x >= 64 && threadIdx.x < 128) {
        int f = threadIdx.x - 64;
        float m   = stats[f] * invN;
        float var = stats[64 + f] * invN - m * m;
        sm[f] = m;
        sv[f] = rsqrtf(var + 1e-5f);
        sg[f] = g[f];
        sb[f] = b[f];
    }
    __syncthreads();
    int n = blockIdx.x * 256 + threadIdx.x;
    if (n >= N) return;
    float a[64];
    const float4* hp = (const float4*)(z + (size_t)n * 64);
    #pragma unroll
    for (int i = 0; i < 16; ++i) {
        float4 v = hp[i];
        a[4 * i] = v.x; a[4 * i + 1] = v.y; a[4 * i + 2] = v.z; a[4 * i + 3] = v.w;
    }
    #pragma unroll
    for (int k = 0; k < 64; ++k) {
        float t = sg[k] * ((a[k] - sm[k]) * sv[k]) + sb[k];
        a[k] = (t > 0.f) ? t : expm1f(t);
    }
    float t1[48];
    for (int j = 0; j < 48; ++j) {
        float acc = bb1[j];
        #pragma unroll
        for (int k = 0; k < 64; ++k) acc += a[k] * w1[k * 48 + j];
        t1[j] = (acc > 0.f) ? acc : expm1f(acc);
    }
    float t2[32];
    for (int j = 0; j < 32; ++j) {
        float acc = bb2[j];
        #pragma unroll
        for (int k = 0; k < 48; ++k) acc += t1[k] * w2[k * 32 + j];
        t2[j] = (acc > 0.f) ? acc : expm1f(acc);
    }
    float t3[16];
    for (int j = 0; j < 16; ++j) {
        float acc = bb3[j];
        #pragma unroll
        for (int k = 0; k < 32; ++k) acc += t2[k] * w3[k * 16 + j];
        t3[j] = (acc > 0.f) ? acc : expm1f(acc);
    }
    float o0 = bb4[0], o1 = bb4[1];
    #pragma unroll
    for (int k = 0; k < 16; ++k) {
        o0 += t3[k] * w4[k * 2 + 0];
        o1 += t3[k] * w4[k * 2 + 1];
    }
    out[(size_t)n * 2 + 0] = o0;
    out[(size_t)n * 2 + 1] = o1;
}

// ---------------------------------------------------------------------------
extern "C" void kernel_launch(void* const* d_in, const int* in_sizes, int n_in,
                              void* d_out, int out_size, void* d_ws, size_t ws_size,
                              hipStream_t stream)
{
    const float* x    = (const float*)d_in[0];
    const int*   ei   = (const int*)d_in[1];
    const float* Wpre = (const float*)d_in[2];
    const float* g0   = (const float*)d_in[3];
    const float* b0   = (const float*)d_in[4];

    const int N = in_sizes[0] / 128;
    const int E = in_sizes[1] / 2;
    const float invN = 1.f / (float)N;

    float* ws      = (float*)d_ws;
    float* h       = ws;                      // N*64
    float* xlr     = h + (size_t)N * 64;      // N*128
    float* z       = xlr + (size_t)N * 128;   // N*64
    float* stats   = z + (size_t)N * 64;      // 5*128
    int*   deg     = (int*)(stats + 5 * 128); // N
    int*   row_ptr = deg + N;                 // N+1
    int*   cursor  = row_ptr + N + 1;         // N
    int*   part    = cursor + N;              // 256
    int*   col     = part + 256;              // E

    const int* srcs = ei;
    const int* dsts = ei + E;
    const int nb = (N + 2047) / 2048;

    // ---- CSR build ----
    hipMemsetAsync(deg, 0, (size_t)N * sizeof(int), stream);
    hipMemsetAsync(stats, 0, 5 * 128 * sizeof(float), stream);
    hist_kernel<<<(E + 255) / 256, 256, 0, stream>>>(dsts, deg, E);
    scan_partials_kernel<<<nb, 256, 0, stream>>>(deg, part, N);
    scan_scan_kernel<<<1, 256, 0, stream>>>(part, nb);
    scan_final_kernel<<<nb, 256, 0, stream>>>(deg, part, row_ptr, cursor, N, E);
    scatter_kernel<<<(E + 255) / 256, 256, 0, stream>>>(srcs, dsts, cursor, col, E);

    // ---- pre-layer: z = x @ Wpre ; stats0 ----
    bn_gemm_kernel<128, 64, 16><<<(N + 15) / 16, 256, 0, stream>>>(
        x, Wpre, nullptr, z, nullptr, nullptr, nullptr, nullptr, N, invN);
    stats_kernel<<<1024, 256, 0, stream>>>(z, stats, N);

    // ---- 4 GATv2 layers ----
    for (int l = 0; l < 4; ++l) {
        const float* Wl  = (const float*)d_in[5 + 5 * l + 0];
        const float* Wr  = (const float*)d_in[5 + 5 * l + 1];
        const float* att = (const float*)d_in[5 + 5 * l + 2];
        // BN params applied on the INPUT side of this layer (previous BN)
        const float* gp = (l == 0) ? g0 : (const float*)d_in[5 + 5 * (l - 1) + 3];
        const float* bp = (l == 0) ? b0 : (const float*)d_in[5 + 5 * (l - 1) + 4];
        float* statsp = stats + 128 * l;

        bn_gemm_kernel<64, 128, 16><<<(N + 15) / 16, 256, 0, stream>>>(
            z, Wl, Wr, xlr, statsp, gp, bp, h, N, invN);
        gat_node_kernel<<<1024, 256, 0, stream>>>(
            row_ptr, col, xlr, att, h, z, stats + 128 * (l + 1), N);
    }

    // ---- MLP head (BN4 fused) ----
    const float* g4  = (const float*)d_in[23];
    const float* b4  = (const float*)d_in[24];
    const float* Wp1 = (const float*)d_in[25]; const float* bp1 = (const float*)d_in[26];
    const float* Wp2 = (const float*)d_in[27]; const float* bp2 = (const float*)d_in[28];
    const float* Wp3 = (const float*)d_in[29]; const float* bp3 = (const float*)d_in[30];
    const float* Wp4 = (const float*)d_in[31]; const float* bp4 = (const float*)d_in[32];
    mlp_kernel<<<(N + 255) / 256, 256, 0, stream>>>(
        z, stats + 512, g4, b4, Wp1, bp1, Wp2, bp2, Wp3, bp3, Wp4, bp4,
        (float*)d_out, N, invN);
}